// Round 1
// baseline (2276.185 us; speedup 1.0000x reference)
//
#include <hip/hip_runtime.h>
#include <cstdint>

#define NSTEPS 100

// 100 per-step threefry subkeys + 1 pad entry so the s+1 prefetch is always
// in-bounds. Passed by value through kernargs (816 B < 4 KB).
struct KeyArr {
    uint32_t k1[NSTEPS + 1];
    uint32_t k2[NSTEPS + 1];
};

__host__ __device__ __forceinline__ uint32_t rotl32(uint32_t x, uint32_t r) {
    return (x << r) | (x >> (32u - r));   // -> v_alignbit_b32, 1 instr
}

// Host-side reference threefry (key derivation only).
static void threefry2x32_host(uint32_t k1, uint32_t k2, uint32_t x0, uint32_t x1,
                              uint32_t& o0, uint32_t& o1) {
    const uint32_t ks2 = k1 ^ k2 ^ 0x1BD11BDAu;
    x0 += k1; x1 += k2;
#define TF_R(r) { x0 += x1; x1 = rotl32(x1, r); x1 ^= x0; }
    TF_R(13u) TF_R(15u) TF_R(26u) TF_R(6u)   x0 += k2;  x1 += ks2 + 1u;
    TF_R(17u) TF_R(29u) TF_R(16u) TF_R(24u)  x0 += ks2; x1 += k1 + 2u;
    TF_R(13u) TF_R(15u) TF_R(26u) TF_R(6u)   x0 += k1;  x1 += k2 + 3u;
    TF_R(17u) TF_R(29u) TF_R(16u) TF_R(24u)  x0 += k2;  x1 += ks2 + 4u;
    TF_R(13u) TF_R(15u) TF_R(26u) TF_R(6u)   x0 += ks2; x1 += k1 + 5u;
#undef TF_R
    o0 = x0; o1 = x1;
}

// Device cipher, 4 independent counters in lockstep so the scheduler keeps
// 4 chains interleaved (ILP ~4 within a wave). Bit-identical to the original:
//  - x1[i] = (base + i) + k2 via c0 = base + k2, then + inline-const i
//    (integer associativity: same bits).
//  - key injections fused into the next round's add -> v_add3_u32.
//  - key-only constants (ks2+c, k1+c, ...) are wave-uniform -> scalar pipe.
__device__ __forceinline__ void tf_bits4(uint32_t k1, uint32_t k2, uint32_t ks2,
                                         uint32_t c0, uint32_t out[4]) {
    uint32_t x0[4], x1[4];
#pragma unroll
    for (int i = 0; i < 4; ++i) {
        x1[i] = c0 + (uint32_t)i;           // = (base+i) + k2
        x0[i] = k1 + x1[i];                 // init(x0=k1) fused with round-1 add
        x1[i] = rotl32(x1[i], 13u); x1[i] ^= x0[i];
    }
#define R4(r)                                                   \
    _Pragma("unroll")                                           \
    for (int i = 0; i < 4; ++i) {                               \
        x0[i] += x1[i]; x1[i] = rotl32(x1[i], r); x1[i] ^= x0[i]; \
    }
#define RI4(r, ka, kb)                                          \
    _Pragma("unroll")                                           \
    for (int i = 0; i < 4; ++i) {                               \
        x1[i] += (kb); x0[i] = x0[i] + (ka) + x1[i];            \
        x1[i] = rotl32(x1[i], r); x1[i] ^= x0[i];               \
    }
    R4(15u) R4(26u) R4(6u)
    RI4(17u, k2,  ks2 + 1u)
    R4(29u) R4(16u) R4(24u)
    RI4(13u, ks2, k1 + 2u)
    R4(15u) R4(26u) R4(6u)
    RI4(17u, k1,  k2 + 3u)
    R4(29u) R4(16u) R4(24u)
    RI4(13u, k2,  ks2 + 4u)
    R4(15u) R4(26u) R4(6u)
#undef R4
#undef RI4
#pragma unroll
    for (int i = 0; i < 4; ++i)
        out[i] = (x0[i] + ks2) ^ (x1[i] + (k1 + 5u));
}

__global__ __launch_bounds__(256, 8)
void DiffusionProcess_21698174780217_kernel(
    const float* __restrict__ x, const float* __restrict__ betas,
    float* __restrict__ out, KeyArr keys, int n4) {
    __shared__ float sb[NSTEPS + 1];
    const int t = threadIdx.x;
    if (t < NSTEPS) sb[t] = __builtin_amdgcn_sqrtf(betas[t] * 2.0f); // sqrt(2*beta)
    else if (t == NSTEPS) sb[NSTEPS] = 0.0f;                        // prefetch pad
    __syncthreads();

    const int gid = blockIdx.x * blockDim.x + t;
    if (gid >= n4) return;
    const uint32_t base = (uint32_t)gid * 4u;
    const float MINVAL = -0.99999994f;      // nextafter(-1, 0) in f32

    float acc0 = 0.f, acc1 = 0.f, acc2 = 0.f, acc3 = 0.f;

    // Software-pipelined uniforms: keys/sb for step s are already in registers
    // when the step starts; prefetch s+1 before the cipher so the s_load /
    // ds_read latency hides under ~350 VALU ops.
    uint32_t k1 = keys.k1[0];
    uint32_t k2 = keys.k2[0];
    float sbs = sb[0];

#pragma unroll 2
    for (int s = 0; s < NSTEPS; ++s) {
        const uint32_t nk1 = keys.k1[s + 1];   // pad entry makes this safe at s=99
        const uint32_t nk2 = keys.k2[s + 1];
        const float nsb = sb[s + 1];

        const uint32_t ks2 = k1 ^ k2 ^ 0x1BD11BDAu;   // uniform -> SALU
        uint32_t r[4];
        tf_bits4(k1, k2, ks2, base + k2, r);

        // Branch-free prefix for all 4 samples first (batches the quarter-rate
        // v_log issues and keeps this phase exec-mask free), then the branchy
        // Giles polynomials. Bit-identical math to the verified kernel:
        //  - (bits>>9)|0x3f800000 as one v_alignbit: funnel(127:bits)>>9.
        //  - t = 1-u^2 via single fma.
        //  - branch compares raw v_log output against -5/ln2; central path
        //    folds *(-ln2) and -2.5 into one fma.
        float u[4], lgv[4];
#pragma unroll
        for (int i = 0; i < 4; ++i) {
            float b = __uint_as_float(__builtin_amdgcn_alignbit(127u, r[i], 9u)); // [1,2)
            float f = b - 1.0f;                 // exact (Sterbenz)
            u[i] = fmaf(f, 2.0f, MINVAL);       // [MINVAL, 0.99999994]
            float au = fabsf(u[i]);             // src modifier, free
            float tt = fmaf(-au, au, 1.0f);     // 1 - u^2, single rounding
            lgv[i] = __builtin_amdgcn_logf(tt); // log2(1-u^2), quarter-rate
        }

        float pu[4];
#pragma unroll
        for (int i = 0; i < 4; ++i) {
            float p;
            if (lgv[i] > -7.2134752f) {         // w = -ln2*lg < 5 (central, 99.67%)
                float w = fmaf(lgv[i], -0.69314718056f, -2.5f);
                p =              2.81022636e-08f;
                p = fmaf(p, w,   3.43273939e-07f);
                p = fmaf(p, w,  -3.5233877e-06f);
                p = fmaf(p, w,  -4.39150654e-06f);
                p = fmaf(p, w,   0.00021858087f);
                p = fmaf(p, w,  -0.00125372503f);
                p = fmaf(p, w,  -0.00417768164f);
                p = fmaf(p, w,   0.246640727f);
                p = fmaf(p, w,   1.50140941f);
            } else {                            // rare tail: ~0.33% of lanes
                float w0 = lgv[i] * -0.69314718056f;
                float w = __builtin_amdgcn_sqrtf(w0) - 3.0f;
                p =             -0.000200214257f;
                p = fmaf(p, w,   0.000100950558f);
                p = fmaf(p, w,   0.00134934322f);
                p = fmaf(p, w,  -0.00367342844f);
                p = fmaf(p, w,   0.00573950773f);
                p = fmaf(p, w,  -0.0076224613f);
                p = fmaf(p, w,   0.00943887047f);
                p = fmaf(p, w,   1.00167406f);
                p = fmaf(p, w,   2.83297682f);
            }
            pu[i] = p * u[i];
        }

        acc0 = fmaf(sbs, pu[0], acc0);
        acc1 = fmaf(sbs, pu[1], acc1);
        acc2 = fmaf(sbs, pu[2], acc2);
        acc3 = fmaf(sbs, pu[3], acc3);

        k1 = nk1; k2 = nk2; sbs = nsb;
    }

    const float4 xv = reinterpret_cast<const float4*>(x)[gid];
    float4 ov;
    ov.x = xv.x + acc0;
    ov.y = xv.y + acc1;
    ov.z = xv.z + acc2;
    ov.w = xv.w + acc3;
    reinterpret_cast<float4*>(out)[gid] = ov;
}

extern "C" void kernel_launch(void* const* d_in, const int* in_sizes, int n_in,
                              void* d_out, int out_size, void* d_ws, size_t ws_size,
                              hipStream_t stream) {
    const float* x = (const float*)d_in[0];
    const float* betas = (const float*)d_in[1];
    float* out = (float*)d_out;
    const int n = in_sizes[0];       // 64*3*256*256 = 12,582,912 (divisible by 4)
    const int n4 = n / 4;

    // jax.random.key(1) -> key data (0, 1).
    // split (partitionable / foldlike): keys[s] = threefry2x32((0,1), (0, s)).
    KeyArr keys;
    for (int s = 0; s < NSTEPS; ++s) {
        uint32_t o0, o1;
        threefry2x32_host(0u, 1u, 0u, (uint32_t)s, o0, o1);
        keys.k1[s] = o0;
        keys.k2[s] = o1;
    }
    keys.k1[NSTEPS] = 0u;            // prefetch pad
    keys.k2[NSTEPS] = 0u;

    const int blocks = (n4 + 255) / 256;
    hipLaunchKernelGGL(DiffusionProcess_21698174780217_kernel,
                       dim3(blocks), dim3(256), 0, stream,
                       x, betas, out, keys, n4);
}